// Round 3
// baseline (746.443 us; speedup 1.0000x reference)
//
#include <hip/hip_runtime.h>

// ---------------- problem constants ----------------
#define B_  8
#define C_  32
#define U_  5
#define V_  5
#define H_  64
#define W_  64

// x / out strides (fp32 elements): [B][32][U][V][H][W]
#define SV_ 4096
#define SU_ 20480
#define SC_ 102400
#define SB_ 3276800

// xT (bf16): [row = ((b*25+u*5+v)*64+h)][cq(4)][w(64)][c8(8)]  -> 4096 B per row
// ws layout (bytes): [0, 52428800) xT ; [BT_OFF, +55296) weight table ; [ZP_OFF, +1024) zero page
#define BT_OFF 52428800ull
#define ZP_OFF (BT_OFF + 55296ull)

typedef short bf16x8 __attribute__((ext_vector_type(8)));
typedef float f32x4 __attribute__((ext_vector_type(4)));

__device__ __forceinline__ unsigned short f2bf(float f) {
    unsigned int u = __builtin_bit_cast(unsigned int, f);
    u = (u + 0x7FFFu + ((u >> 16) & 1u)) >> 16;   // RNE
    return (unsigned short)u;
}

__device__ __forceinline__ f32x4 mfma16(bf16x8 a, bf16x8 b, f32x4 c) {
    return __builtin_amdgcn_mfma_f32_16x16x32_bf16(a, b, c, 0, 0, 0);
}

// ---------------- K1: x fp32 [B,C,U,V,H,W] -> xT bf16 [row][cq][w][c8] ----------------
__global__ __launch_bounds__(256)
void k_transpose(const float* __restrict__ x, unsigned short* __restrict__ xT)
{
    __shared__ float tl[C_ * 4 * 64];   // [c][h(4)][w(64)] fp32, 32 KB
    const int tid = threadIdx.x;
    int blk = blockIdx.x;
    const int hq = blk & 15; blk >>= 4;
    const int v = blk % 5; blk /= 5;
    const int u = blk % 5;
    const int b = blk / 5;
    const int h0 = hq * 4;

    const float* src = x + (size_t)b * SB_ + (size_t)u * SU_ + (size_t)v * SV_ + h0 * 64;
#pragma unroll
    for (int i = 0; i < 8; ++i) {
        const int e = tid + i * 256;       // 2048 float4s total
        const int c = e >> 6;
        const int rem = e & 63;
        const int h = rem >> 4;
        const int w4 = (rem & 15) * 4;
        const float4 val = *(const float4*)(src + (size_t)c * SC_ + h * 64 + w4);
        *(float4*)(tl + c * 256 + h * 64 + w4) = val;
    }
    __syncthreads();

    const int h = tid >> 6;
    const int w = tid & 63;
    unsigned short* dst = xT + (size_t)((b * 25 + u * 5 + v) * 64 + h0 + h) * 2048;
#pragma unroll
    for (int cq = 0; cq < 4; ++cq) {
        unsigned short s[8];
#pragma unroll
        for (int j = 0; j < 8; ++j)
            s[j] = f2bf(tl[(cq * 8 + j) * 256 + h * 64 + w]);
        uint4 o;
        o.x = (unsigned)s[0] | ((unsigned)s[1] << 16);
        o.y = (unsigned)s[2] | ((unsigned)s[3] << 16);
        o.z = (unsigned)s[4] | ((unsigned)s[5] << 16);
        o.w = (unsigned)s[6] | ((unsigned)s[7] << 16);
        *(uint4*)(dst + cq * 512 + w * 8) = o;
    }
}

// ---------------- K2: weights -> A-frag table bf16 ; + zero page ----------------
// frag f = br*27 + t0*9 + t1*3 + t2 ; per frag: [oc(8)][c(32)] bf16 = 512 B
__global__ __launch_bounds__(256)
void k_weights(const float* __restrict__ w0, const float* __restrict__ w1,
               const float* __restrict__ w2, const float* __restrict__ w3,
               unsigned short* __restrict__ btab, uint4* __restrict__ zp)
{
    const int br = blockIdx.x;
    const float* wp = (br == 0) ? w0 : (br == 1) ? w1 : (br == 2) ? w2 : w3;
    const int oc = threadIdx.x >> 5;
    const int c  = threadIdx.x & 31;
#pragma unroll 3
    for (int tap = 0; tap < 27; ++tap)
        btab[(size_t)(br * 27 + tap) * 256 + oc * 32 + c] = f2bf(wp[(size_t)oc * 864 + c * 27 + tap]);
    if (br == 0 && threadIdx.x < 64)
        zp[threadIdx.x] = make_uint4(0u, 0u, 0u, 0u);
}

// ---------------- K3: main MFMA kernel ----------------
// block = (b,u,v, 4 h-rows), 512 threads = 8 waves: wave = (hp2 = wave>>2)*2 h-rows, w-tile (wave&3)*16
// LDS: 18 planes (3 dv x 6 hrow) x [4 cq][66 w][16 B] = 76032 B  (slot w+1; slots 0,65 = zero halos)
// MFMA: A = W[oc16][c32] (oc = lane&7 repl), B = x[c32][w16], D[oc][w]: w = lane&15, oc = q*4+reg
__global__ __launch_bounds__(512, 4)
void k_main(const unsigned short* __restrict__ xT,
            const unsigned short* __restrict__ btabu,
            const uint4* __restrict__ zp,
            const float* __restrict__ bb0, const float* __restrict__ aa0,
            const float* __restrict__ bb1, const float* __restrict__ aa1,
            const float* __restrict__ bb2, const float* __restrict__ aa2,
            const float* __restrict__ bb3, const float* __restrict__ aa3,
            float* __restrict__ out)
{
    __shared__ alignas(16) char xlds[76032];

    const int tid = threadIdx.x;
    int blk = blockIdx.x;
    const int hs = blk & 15; blk >>= 4;
    const int v = blk % 5; blk /= 5;
    const int u = blk % 5;
    const int b = blk / 5;
    const int h0 = hs * 4;

    const int wave = tid >> 6;
    const int lane = tid & 63;
    const int n = lane & 15;
    const int q = lane >> 4;
    const int w0 = (wave & 3) * 16;
    const int rbase = (wave >> 2) * 2;     // first output row (relative) of this wave

    // zero the w-halos once (never overwritten by staging)
    if (tid < 144) {
        const int p  = tid >> 3;
        const int rr = tid & 7;
        *(uint4*)(xlds + p * 4224 + (rr >> 1) * 1056 + (rr & 1) * 1040) = make_uint4(0, 0, 0, 0);
    }

    f32x4 acc[4][2];
#pragma unroll
    for (int i = 0; i < 4; ++i)
#pragma unroll
        for (int j = 0; j < 2; ++j) acc[i][j] = (f32x4)0.f;

    const char* bt = (const char*)btabu;
    const char* xTb = (const char*)xT;
    const char* zpb = (const char*)zp;
    const int lane_off = q * 1056 + (w0 + n) * 16;   // per-lane base within a plane

    for (int du = 0; du < 3; ++du) {
        const int up = u + du - 1;
        const bool u_ok = (up >= 0) && (up < 5);
        __syncthreads();                    // prior-iter reads (and halo zeros) done
        if (u_ok) {
            // 72 staging items = 18 planes x 4 cq ; 9 per wave, 1 KB each
#pragma unroll
            for (int i = 0; i < 9; ++i) {
                const int item = wave * 9 + i;
                const int p  = item >> 2;
                const int cq = item & 3;
                const int dv = p / 6;
                const int hr = p % 6;
                const int vp = v + dv - 1;
                const int hp = h0 + hr - 1;
                const char* srcb;
                if (vp >= 0 && vp < 5 && hp >= 0 && hp < 64)
                    srcb = xTb + (size_t)((b * 25 + up * 5 + vp) * 64 + hp) * 4096 + cq * 1024;
                else
                    srcb = zpb;
                __builtin_amdgcn_global_load_lds(
                    (const __attribute__((address_space(1))) unsigned int*)(srcb + lane * 16),
                    (__attribute__((address_space(3))) unsigned int*)(void*)(xlds + p * 4224 + cq * 1056 + 16),
                    16, 0, 0);
            }
        }
        __syncthreads();                    // staging visible
        if (!u_ok) continue;

        auto AF = [&](int dv, int row, int dw) -> bf16x8 {
            return *(const bf16x8*)(xlds + (dv * 6 + rbase + row) * 4224 + dw * 16 + lane_off);
        };
        auto WF = [&](int f) -> bf16x8 {
            return *(const bf16x8*)(bt + f * 512 + (n & 7) * 64 + q * 16);
        };

        // br0: uvx (conv u,v,h): taps (du,dv,dh); dw neutral (=1)
#pragma unroll
        for (int dv = 0; dv < 3; ++dv) {
            const int fb = du * 9 + dv * 3;
            bf16x8 Wf0 = WF(fb + 0), Wf1 = WF(fb + 1), Wf2 = WF(fb + 2);
#pragma unroll
            for (int hh = 0; hh < 2; ++hh) {
                acc[0][hh] = mfma16(Wf0, AF(dv, hh + 0, 1), acc[0][hh]);
                acc[0][hh] = mfma16(Wf1, AF(dv, hh + 1, 1), acc[0][hh]);
                acc[0][hh] = mfma16(Wf2, AF(dv, hh + 2, 1), acc[0][hh]);
            }
        }
        // br1: uvy (conv u,v,w): taps (du,dv,dw); row = hh+1
#pragma unroll
        for (int dv = 0; dv < 3; ++dv) {
            const int fb = 27 + du * 9 + dv * 3;
            bf16x8 Wf0 = WF(fb + 0), Wf1 = WF(fb + 1), Wf2 = WF(fb + 2);
#pragma unroll
            for (int hh = 0; hh < 2; ++hh) {
                acc[1][hh] = mfma16(Wf0, AF(dv, hh + 1, 0), acc[1][hh]);
                acc[1][hh] = mfma16(Wf1, AF(dv, hh + 1, 1), acc[1][hh]);
                acc[1][hh] = mfma16(Wf2, AF(dv, hh + 1, 2), acc[1][hh]);
            }
        }
        // br2: uxy (conv u,h,w): taps (du,dh,dw); dv neutral (=1)
#pragma unroll
        for (int dh = 0; dh < 3; ++dh) {
            const int fb = 54 + du * 9 + dh * 3;
            bf16x8 Wf0 = WF(fb + 0), Wf1 = WF(fb + 1), Wf2 = WF(fb + 2);
#pragma unroll
            for (int hh = 0; hh < 2; ++hh) {
                acc[2][hh] = mfma16(Wf0, AF(1, hh + dh, 0), acc[2][hh]);
                acc[2][hh] = mfma16(Wf1, AF(1, hh + dh, 1), acc[2][hh]);
                acc[2][hh] = mfma16(Wf2, AF(1, hh + dh, 2), acc[2][hh]);
            }
        }
        // br3: vxy (conv v,h,w): taps (dv,dh,dw); only du==1
        if (du == 1) {
#pragma unroll
            for (int dv = 0; dv < 3; ++dv)
#pragma unroll
                for (int dh = 0; dh < 3; ++dh) {
                    const int fb = 81 + dv * 9 + dh * 3;
                    bf16x8 Wf0 = WF(fb + 0), Wf1 = WF(fb + 1), Wf2 = WF(fb + 2);
#pragma unroll
                    for (int hh = 0; hh < 2; ++hh) {
                        acc[3][hh] = mfma16(Wf0, AF(dv, hh + dh, 0), acc[3][hh]);
                        acc[3][hh] = mfma16(Wf1, AF(dv, hh + dh, 1), acc[3][hh]);
                        acc[3][hh] = mfma16(Wf2, AF(dv, hh + dh, 2), acc[3][hh]);
                    }
                }
        }
    }

    // ---------------- epilogue: bias + PReLU + store ----------------
    const float alph[4] = { aa0[0], aa1[0], aa2[0], aa3[0] };
    float* op = out + (size_t)b * SB_ + (size_t)u * SU_ + (size_t)v * SV_ + w0 + n;
    const bool act = (q < 2);
#pragma unroll
    for (int br = 0; br < 4; ++br) {
        const float* bp = (br == 0) ? bb0 : (br == 1) ? bb1 : (br == 2) ? bb2 : bb3;
        const f32x4 bv = *(const f32x4*)(bp + (q & 1) * 4);
#pragma unroll
        for (int hh = 0; hh < 2; ++hh) {
            const int h = h0 + rbase + hh;
#pragma unroll
            for (int r = 0; r < 4; ++r) {
                float val = acc[br][hh][r] + bv[r];
                val = (val >= 0.f) ? val : alph[br] * val;
                if (act)
                    op[(size_t)(br * 8 + q * 4 + r) * SC_ + (size_t)h * 64] = val;
            }
        }
    }
}

extern "C" void kernel_launch(void* const* d_in, const int* in_sizes, int n_in,
                              void* d_out, int out_size, void* d_ws, size_t ws_size,
                              hipStream_t stream) {
    const float* x  = (const float*)d_in[0];
    const float* w0 = (const float*)d_in[1];
    const float* b0 = (const float*)d_in[2];
    const float* a0 = (const float*)d_in[3];
    const float* w1 = (const float*)d_in[4];
    const float* b1 = (const float*)d_in[5];
    const float* a1 = (const float*)d_in[6];
    const float* w2 = (const float*)d_in[7];
    const float* b2 = (const float*)d_in[8];
    const float* a2 = (const float*)d_in[9];
    const float* w3 = (const float*)d_in[10];
    const float* b3 = (const float*)d_in[11];
    const float* a3 = (const float*)d_in[12];
    float* out = (float*)d_out;

    unsigned short* xT = (unsigned short*)d_ws;
    unsigned short* bt = (unsigned short*)((char*)d_ws + BT_OFF);
    uint4* zp = (uint4*)((char*)d_ws + ZP_OFF);

    k_weights<<<4, 256, 0, stream>>>(w0, w1, w2, w3, bt, zp);
    k_transpose<<<B_ * U_ * V_ * (H_ / 4), 256, 0, stream>>>(x, xT);   // 3200 blocks
    k_main<<<B_ * U_ * V_ * (H_ / 4), 512, 0, stream>>>(               // 3200 blocks
        xT, bt, zp, b0, a0, b1, a1, b2, a2, b3, a3, out);
}

// Round 4
// 375.150 us; speedup vs baseline: 1.9897x; 1.9897x over previous
//
#include <hip/hip_runtime.h>

// ---------------- problem constants ----------------
#define B_  8
#define C_  32
#define U_  5
#define V_  5
#define H_  64
#define W_  64

// x / out strides (fp32 elements): [B][32][U][V][H][W]
#define SV_ 4096
#define SU_ 20480
#define SC_ 102400
#define SB_ 3276800

// xT (bf16): [row = ((b*25+u*5+v)*64+h)][cq(4)][w(64)][c8(8)]  -> 4096 B per row
// ws layout (bytes): [0, 52428800) xT ; [BT_OFF, +55296) weight table ; [ZP_OFF, +1024) zero page
#define BT_OFF 52428800ull
#define ZP_OFF (BT_OFF + 55296ull)

typedef short bf16x8 __attribute__((ext_vector_type(8)));
typedef float f32x4 __attribute__((ext_vector_type(4)));

__device__ __forceinline__ unsigned short f2bf(float f) {
    unsigned int u = __builtin_bit_cast(unsigned int, f);
    u = (u + 0x7FFFu + ((u >> 16) & 1u)) >> 16;   // RNE
    return (unsigned short)u;
}

__device__ __forceinline__ f32x4 mfma16(bf16x8 a, bf16x8 b, f32x4 c) {
    return __builtin_amdgcn_mfma_f32_16x16x32_bf16(a, b, c, 0, 0, 0);
}

// ---------------- K1: x fp32 [B,C,U,V,H,W] -> xT bf16 [row][cq][w][c8] ----------------
__global__ __launch_bounds__(256)
void k_transpose(const float* __restrict__ x, unsigned short* __restrict__ xT)
{
    __shared__ float tl[C_ * 4 * 64];   // [c][h(4)][w(64)] fp32, 32 KB
    const int tid = threadIdx.x;
    int blk = blockIdx.x;
    const int hq = blk & 15; blk >>= 4;
    const int v = blk % 5; blk /= 5;
    const int u = blk % 5;
    const int b = blk / 5;
    const int h0 = hq * 4;

    const float* src = x + (size_t)b * SB_ + (size_t)u * SU_ + (size_t)v * SV_ + h0 * 64;
#pragma unroll
    for (int i = 0; i < 8; ++i) {
        const int e = tid + i * 256;       // 2048 float4s total
        const int c = e >> 6;
        const int rem = e & 63;
        const int h = rem >> 4;
        const int w4 = (rem & 15) * 4;
        const float4 val = *(const float4*)(src + (size_t)c * SC_ + h * 64 + w4);
        *(float4*)(tl + c * 256 + h * 64 + w4) = val;
    }
    __syncthreads();

    const int h = tid >> 6;
    const int w = tid & 63;
    unsigned short* dst = xT + (size_t)((b * 25 + u * 5 + v) * 64 + h0 + h) * 2048;
#pragma unroll
    for (int cq = 0; cq < 4; ++cq) {
        unsigned short s[8];
#pragma unroll
        for (int j = 0; j < 8; ++j)
            s[j] = f2bf(tl[(cq * 8 + j) * 256 + h * 64 + w]);
        uint4 o;
        o.x = (unsigned)s[0] | ((unsigned)s[1] << 16);
        o.y = (unsigned)s[2] | ((unsigned)s[3] << 16);
        o.z = (unsigned)s[4] | ((unsigned)s[5] << 16);
        o.w = (unsigned)s[6] | ((unsigned)s[7] << 16);
        *(uint4*)(dst + cq * 512 + w * 8) = o;
    }
}

// ---------------- K2: weights -> A-frag table bf16 ; + zero page ----------------
// one block per frag f = br*27 + tap ; per frag: [oc(8)][c(32)] bf16 = 512 B
__global__ __launch_bounds__(256)
void k_weights(const float* __restrict__ w0, const float* __restrict__ w1,
               const float* __restrict__ w2, const float* __restrict__ w3,
               unsigned short* __restrict__ btab, uint4* __restrict__ zp)
{
    const int f = blockIdx.x;          // 0..107
    const int br = f / 27;
    const int tap = f % 27;
    const float* wp = (br == 0) ? w0 : (br == 1) ? w1 : (br == 2) ? w2 : w3;
    const int oc = threadIdx.x >> 5;
    const int c  = threadIdx.x & 31;
    btab[(size_t)f * 256 + oc * 32 + c] = f2bf(wp[(size_t)oc * 864 + c * 27 + tap]);
    if (f == 0 && threadIdx.x < 64)
        zp[threadIdx.x] = make_uint4(0u, 0u, 0u, 0u);
}

// ---------------- K3: main MFMA kernel ----------------
// block = (b,u,v, 4 h-rows), 512 threads = 8 waves: wave rows rbase=(wave>>2)*2 (+0,1), w-tile (wave&3)*16
// LDS: 18 planes (3 dv x 6 hrow) x [4 cq][66 w][16 B] = 76032 B  (slot w+1; slots 0,65 zero halos)
// MFMA: A = W[oc16][c32] (oc = lane&7 repl), B = x[c32][w16], D[oc][w]: w = lane&15, oc = q*4+reg
// launch_bounds (512,2): 2 blocks/CU -> 128-VGPR cap. (512,4) spilled acc to scratch (r3: 1.38 GB writes).
__global__ __launch_bounds__(512, 2)
void k_main(const unsigned short* __restrict__ xT,
            const unsigned short* __restrict__ btabu,
            const uint4* __restrict__ zp,
            const float* __restrict__ bb0, const float* __restrict__ aa0,
            const float* __restrict__ bb1, const float* __restrict__ aa1,
            const float* __restrict__ bb2, const float* __restrict__ aa2,
            const float* __restrict__ bb3, const float* __restrict__ aa3,
            float* __restrict__ out)
{
    __shared__ alignas(16) char xlds[76032];

    const int tid = threadIdx.x;
    int blk = blockIdx.x;
    const int hs = blk & 15; blk >>= 4;
    const int v = blk % 5; blk /= 5;
    const int u = blk % 5;
    const int b = blk / 5;
    const int h0 = hs * 4;

    const int wave = tid >> 6;
    const int lane = tid & 63;
    const int n = lane & 15;
    const int q = lane >> 4;
    const int w0 = (wave & 3) * 16;
    const int rbase = (wave >> 2) * 2;

    // zero the w-halos once (never overwritten by staging)
    if (tid < 144) {
        const int p  = tid >> 3;
        const int rr = tid & 7;
        *(uint4*)(xlds + p * 4224 + (rr >> 1) * 1056 + (rr & 1) * 1040) = make_uint4(0, 0, 0, 0);
    }

    f32x4 acc[4][2];
#pragma unroll
    for (int i = 0; i < 4; ++i)
#pragma unroll
        for (int j = 0; j < 2; ++j) acc[i][j] = (f32x4)0.f;

    const char* bt = (const char*)btabu;
    const char* xTb = (const char*)xT;
    const char* zpb = (const char*)zp;
    const int lane_off = q * 1056 + (w0 + n) * 16;

    for (int du = 0; du < 3; ++du) {
        const int up = u + du - 1;
        const bool u_ok = (up >= 0) && (up < 5);
        __syncthreads();                    // prior-iter reads (and halo zeros) done
        if (u_ok) {
            // 72 staging items = 18 planes x 4 cq ; 9 per wave, 1 KB each
#pragma unroll
            for (int i = 0; i < 9; ++i) {
                const int item = wave * 9 + i;
                const int p  = item >> 2;
                const int cq = item & 3;
                const int dv = p / 6;
                const int hr = p % 6;
                const int vp = v + dv - 1;
                const int hp = h0 + hr - 1;
                const char* srcb;
                if (vp >= 0 && vp < 5 && hp >= 0 && hp < 64)
                    srcb = xTb + (size_t)((b * 25 + up * 5 + vp) * 64 + hp) * 4096 + cq * 1024;
                else
                    srcb = zpb;
                __builtin_amdgcn_global_load_lds(
                    (const __attribute__((address_space(1))) unsigned int*)(srcb + lane * 16),
                    (__attribute__((address_space(3))) unsigned int*)(void*)(xlds + p * 4224 + cq * 1056 + 16),
                    16, 0, 0);
            }
        }
        __syncthreads();                    // staging visible
        if (!u_ok) continue;

        auto WF = [&](int f) -> bf16x8 {
            return *(const bf16x8*)(bt + f * 512 + (n & 7) * 64 + q * 16);
        };

#pragma unroll
        for (int dv = 0; dv < 3; ++dv) {
            // load the 12 distinct x-frags for this (du,dv) into registers once
            bf16x8 F[4][3];
#pragma unroll
            for (int r = 0; r < 4; ++r)
#pragma unroll
                for (int dw = 0; dw < 3; ++dw)
                    F[r][dw] = *(const bf16x8*)(xlds + (dv * 6 + rbase + r) * 4224
                                                + dw * 16 + lane_off);

            // br0: uvx (conv u,v,h): taps (du,dv,t); dw neutral
#pragma unroll
            for (int t = 0; t < 3; ++t) {
                const bf16x8 Wf = WF(du * 9 + dv * 3 + t);
                acc[0][0] = mfma16(Wf, F[t + 0][1], acc[0][0]);
                acc[0][1] = mfma16(Wf, F[t + 1][1], acc[0][1]);
            }
            // br1: uvy (conv u,v,w): taps (du,dv,dw); row = hh+1
#pragma unroll
            for (int dw = 0; dw < 3; ++dw) {
                const bf16x8 Wf = WF(27 + du * 9 + dv * 3 + dw);
                acc[1][0] = mfma16(Wf, F[1][dw], acc[1][0]);
                acc[1][1] = mfma16(Wf, F[2][dw], acc[1][1]);
            }
            // br2: uxy (conv u,h,w): taps (du,dh,dw); dv neutral (==1)
            if (dv == 1) {
#pragma unroll
                for (int dh = 0; dh < 3; ++dh)
#pragma unroll
                    for (int dw = 0; dw < 3; ++dw) {
                        const bf16x8 Wf = WF(54 + du * 9 + dh * 3 + dw);
                        acc[2][0] = mfma16(Wf, F[dh + 0][dw], acc[2][0]);
                        acc[2][1] = mfma16(Wf, F[dh + 1][dw], acc[2][1]);
                    }
            }
            // br3: vxy (conv v,h,w): taps (dv,dh,dw); du neutral (==1)
            if (du == 1) {
#pragma unroll
                for (int dh = 0; dh < 3; ++dh)
#pragma unroll
                    for (int dw = 0; dw < 3; ++dw) {
                        const bf16x8 Wf = WF(81 + dv * 9 + dh * 3 + dw);
                        acc[3][0] = mfma16(Wf, F[dh + 0][dw], acc[3][0]);
                        acc[3][1] = mfma16(Wf, F[dh + 1][dw], acc[3][1]);
                    }
            }
        }
    }

    // ---------------- epilogue: bias + PReLU + store ----------------
    const float alph[4] = { aa0[0], aa1[0], aa2[0], aa3[0] };
    float* op = out + (size_t)b * SB_ + (size_t)u * SU_ + (size_t)v * SV_ + w0 + n;
    const bool act = (q < 2);
#pragma unroll
    for (int br = 0; br < 4; ++br) {
        const float* bp = (br == 0) ? bb0 : (br == 1) ? bb1 : (br == 2) ? bb2 : bb3;
        const f32x4 bv = *(const f32x4*)(bp + (q & 1) * 4);
#pragma unroll
        for (int hh = 0; hh < 2; ++hh) {
            const int h = h0 + rbase + hh;
#pragma unroll
            for (int r = 0; r < 4; ++r) {
                float val = acc[br][hh][r] + bv[r];
                val = (val >= 0.f) ? val : alph[br] * val;
                if (act)
                    op[(size_t)(br * 8 + q * 4 + r) * SC_ + (size_t)h * 64] = val;
            }
        }
    }
}

extern "C" void kernel_launch(void* const* d_in, const int* in_sizes, int n_in,
                              void* d_out, int out_size, void* d_ws, size_t ws_size,
                              hipStream_t stream) {
    const float* x  = (const float*)d_in[0];
    const float* w0 = (const float*)d_in[1];
    const float* b0 = (const float*)d_in[2];
    const float* a0 = (const float*)d_in[3];
    const float* w1 = (const float*)d_in[4];
    const float* b1 = (const float*)d_in[5];
    const float* a1 = (const float*)d_in[6];
    const float* w2 = (const float*)d_in[7];
    const float* b2 = (const float*)d_in[8];
    const float* a2 = (const float*)d_in[9];
    const float* w3 = (const float*)d_in[10];
    const float* b3 = (const float*)d_in[11];
    const float* a3 = (const float*)d_in[12];
    float* out = (float*)d_out;

    unsigned short* xT = (unsigned short*)d_ws;
    unsigned short* bt = (unsigned short*)((char*)d_ws + BT_OFF);
    uint4* zp = (uint4*)((char*)d_ws + ZP_OFF);

    k_weights<<<108, 256, 0, stream>>>(w0, w1, w2, w3, bt, zp);
    k_transpose<<<B_ * U_ * V_ * (H_ / 4), 256, 0, stream>>>(x, xT);   // 3200 blocks
    k_main<<<B_ * U_ * V_ * (H_ / 4), 512, 0, stream>>>(               // 3200 blocks
        xT, bt, zp, b0, a0, b1, a1, b2, a2, b3, a3, out);
}

// Round 5
// 292.600 us; speedup vs baseline: 2.5511x; 1.2821x over previous
//
#include <hip/hip_runtime.h>

// ---------------- problem constants ----------------
#define B_  8
#define C_  32
#define U_  5
#define V_  5
#define H_  64
#define W_  64

// x / out strides (fp32 elements): [B][32][U][V][H][W]
#define SV_ 4096
#define SU_ 20480
#define SC_ 102400
#define SB_ 3276800

// xT (bf16, padded): [row = ((b*25+u*5+v)*64+h)][cq(4)][wslot(66)][c8(8)]
//   wslot = w+1 ; slots 0 and 65 are zeros (SAME padding in w for free)
//   row stride = 4*66*16 = 4224 B ; cq stride = 1056 B ; total 12800*4224 = 54067200 B
// btab (bf16): per frag f (108): [q(4)][oc(8)][c8(8)] = 512 B  -> 55296 B
// ws layout: [0, 54067200) xT ; [BT_OFF, +55296) btab
#define XROW 4224
#define BT_OFF 54067200ull

typedef short bf16x8 __attribute__((ext_vector_type(8)));
typedef float f32x4 __attribute__((ext_vector_type(4)));

__device__ __forceinline__ unsigned short f2bf(float f) {
    unsigned int u = __builtin_bit_cast(unsigned int, f);
    u = (u + 0x7FFFu + ((u >> 16) & 1u)) >> 16;   // RNE
    return (unsigned short)u;
}

__device__ __forceinline__ f32x4 mfma16(bf16x8 a, bf16x8 b, f32x4 c) {
    return __builtin_amdgcn_mfma_f32_16x16x32_bf16(a, b, c, 0, 0, 0);
}

// ---------------- K1: x fp32 [B,C,U,V,H,W] -> padded xT ----------------
__global__ __launch_bounds__(256)
void k_transpose(const float* __restrict__ x, unsigned short* __restrict__ xT)
{
    __shared__ float tl[C_ * 4 * 64];   // [c][h(4)][w(64)] fp32, 32 KB
    const int tid = threadIdx.x;
    int blk = blockIdx.x;
    const int hq = blk & 15; blk >>= 4;
    const int v = blk % 5; blk /= 5;
    const int u = blk % 5;
    const int b = blk / 5;
    const int h0 = hq * 4;

    const float* src = x + (size_t)b * SB_ + (size_t)u * SU_ + (size_t)v * SV_ + h0 * 64;
#pragma unroll
    for (int i = 0; i < 8; ++i) {
        const int e = tid + i * 256;
        const int c = e >> 6;
        const int rem = e & 63;
        const int h = rem >> 4;
        const int w4 = (rem & 15) * 4;
        const float4 val = *(const float4*)(src + (size_t)c * SC_ + h * 64 + w4);
        *(float4*)(tl + c * 256 + h * 64 + w4) = val;
    }
    __syncthreads();

    const int h = tid >> 6;
    const int w = tid & 63;
    unsigned short* dst = xT + (size_t)((b * 25 + u * 5 + v) * 64 + h0 + h) * (XROW / 2);
    const uint4 z = make_uint4(0u, 0u, 0u, 0u);
#pragma unroll
    for (int cq = 0; cq < 4; ++cq) {
        unsigned short s[8];
#pragma unroll
        for (int j = 0; j < 8; ++j)
            s[j] = f2bf(tl[(cq * 8 + j) * 256 + h * 64 + w]);
        uint4 o;
        o.x = (unsigned)s[0] | ((unsigned)s[1] << 16);
        o.y = (unsigned)s[2] | ((unsigned)s[3] << 16);
        o.z = (unsigned)s[4] | ((unsigned)s[5] << 16);
        o.w = (unsigned)s[6] | ((unsigned)s[7] << 16);
        *(uint4*)(dst + cq * 528 + (w + 1) * 8) = o;           // wslot = w+1
        if (w == 0)  *(uint4*)(dst + cq * 528 + 0)       = z;  // wslot 0
        if (w == 63) *(uint4*)(dst + cq * 528 + 65 * 8)  = z;  // wslot 65
    }
}

// ---------------- K2: weights -> A-frag table [f][q][oc][c8] bf16 ----------------
__global__ __launch_bounds__(256)
void k_weights(const float* __restrict__ w0, const float* __restrict__ w1,
               const float* __restrict__ w2, const float* __restrict__ w3,
               unsigned short* __restrict__ btab)
{
    const int f = blockIdx.x;          // 0..107
    const int br = f / 27;
    const int tap = f % 27;
    const float* wp = (br == 0) ? w0 : (br == 1) ? w1 : (br == 2) ? w2 : w3;
    const int q  = threadIdx.x >> 6;
    const int oc = (threadIdx.x >> 3) & 7;
    const int j  = threadIdx.x & 7;
    btab[(size_t)f * 256 + q * 64 + oc * 8 + j] =
        f2bf(wp[(size_t)oc * 864 + (q * 8 + j) * 27 + tap]);
}

// ---------------- K3: main MFMA kernel (no x-LDS, one barrier) ----------------
// block = (b,u,v, 4 h-rows), 512 thr = 8 waves: w-tile (wave&3)*16, h-pair rbase=(wave>>2)*2
// x-frags loaded directly from padded xT (global, L2/L3); weights in LDS (conflict-free)
// MFMA: A = W[oc16][c32] (oc = lane&7 repl), B = x[c32][w16], D: w = lane&15, oc = q*4+reg
__global__ __launch_bounds__(512, 2)
void k_main(const unsigned short* __restrict__ xT,
            const unsigned short* __restrict__ btabu,
            const float* __restrict__ bb0, const float* __restrict__ aa0,
            const float* __restrict__ bb1, const float* __restrict__ aa1,
            const float* __restrict__ bb2, const float* __restrict__ aa2,
            const float* __restrict__ bb3, const float* __restrict__ aa3,
            float* __restrict__ out)
{
    __shared__ alignas(16) char wlds[55296];

    const int tid = threadIdx.x;
    const int blk = blockIdx.x;
    // XCD-aware swizzle: the 16 hs-blocks of one (b,u,v) land on one XCD
    const int buv = (blk & 7) + 8 * (blk >> 7);
    const int hs  = (blk >> 3) & 15;
    const int v = buv % 5;
    const int u = (buv / 5) % 5;
    const int b = buv / 25;
    const int h0 = hs * 4;

    // stage weight table to LDS (one time)
    {
        const uint4* g = (const uint4*)btabu;
        uint4* l = (uint4*)wlds;
#pragma unroll
        for (int i = 0; i < 7; ++i) {
            const int e = tid + i * 512;
            if (e < 3456) l[e] = g[e];
        }
    }
    __syncthreads();   // the only barrier

    const int wave = tid >> 6;
    const int lane = tid & 63;
    const int n = lane & 15;
    const int q = lane >> 4;
    const int w0 = (wave & 3) * 16;
    const int rbase = (wave >> 2) * 2;

    f32x4 acc[4][2];
#pragma unroll
    for (int i = 0; i < 4; ++i)
#pragma unroll
        for (int j = 0; j < 2; ++j) acc[i][j] = (f32x4)0.f;

    const char* xTb = (const char*)xT;
    const int lane_off = q * 1056 + (w0 + n) * 16;   // + dw*16 per-frag imm

    auto WF = [&](int f) -> bf16x8 {
        return *(const bf16x8*)(wlds + f * 512 + q * 128 + (n & 7) * 16);
    };
    const bf16x8 zf = {0, 0, 0, 0, 0, 0, 0, 0};

#pragma unroll
    for (int du = 0; du < 3; ++du) {
        const int up = u + du - 1;
        if (up < 0 || up >= 5) continue;              // wave-uniform; zero contribution
#pragma unroll
        for (int dv = 0; dv < 3; ++dv) {
            const int vp = v + dv - 1;
            if (vp < 0 || vp >= 5) continue;          // wave-uniform; zero contribution

            const size_t rowb = (size_t)((b * 25 + up * 5 + vp) * 64) * XROW;
            bf16x8 F[4][3];
#pragma unroll
            for (int r = 0; r < 4; ++r) {
                const int hr = h0 + rbase + r - 1;
                if (hr < 0 || hr >= 64) {
                    F[r][0] = zf; F[r][1] = zf; F[r][2] = zf;
                } else {
                    const char* p = xTb + rowb + (size_t)hr * XROW + lane_off;
#pragma unroll
                    for (int dw = 0; dw < 3; ++dw)
                        F[r][dw] = *(const bf16x8*)(p + dw * 16);
                }
            }

            // br0: uvx (conv u,v,h): taps (du,dv,t); dw neutral
#pragma unroll
            for (int t = 0; t < 3; ++t) {
                const bf16x8 Wf = WF(du * 9 + dv * 3 + t);
                acc[0][0] = mfma16(Wf, F[t + 0][1], acc[0][0]);
                acc[0][1] = mfma16(Wf, F[t + 1][1], acc[0][1]);
            }
            // br1: uvy (conv u,v,w): taps (du,dv,dw); row = hh+1
#pragma unroll
            for (int dw = 0; dw < 3; ++dw) {
                const bf16x8 Wf = WF(27 + du * 9 + dv * 3 + dw);
                acc[1][0] = mfma16(Wf, F[1][dw], acc[1][0]);
                acc[1][1] = mfma16(Wf, F[2][dw], acc[1][1]);
            }
            // br2: uxy (conv u,h,w): taps (du,dh,dw); dv neutral (==1)
            if (dv == 1) {
#pragma unroll
                for (int dh = 0; dh < 3; ++dh)
#pragma unroll
                    for (int dw = 0; dw < 3; ++dw) {
                        const bf16x8 Wf = WF(54 + du * 9 + dh * 3 + dw);
                        acc[2][0] = mfma16(Wf, F[dh + 0][dw], acc[2][0]);
                        acc[2][1] = mfma16(Wf, F[dh + 1][dw], acc[2][1]);
                    }
            }
            // br3: vxy (conv v,h,w): taps (dv,dh,dw); du neutral (==1)
            if (du == 1) {
#pragma unroll
                for (int dh = 0; dh < 3; ++dh)
#pragma unroll
                    for (int dw = 0; dw < 3; ++dw) {
                        const bf16x8 Wf = WF(81 + dv * 9 + dh * 3 + dw);
                        acc[3][0] = mfma16(Wf, F[dh + 0][dw], acc[3][0]);
                        acc[3][1] = mfma16(Wf, F[dh + 1][dw], acc[3][1]);
                    }
            }
        }
    }

    // ---------------- epilogue: bias + PReLU + store ----------------
    const float alph[4] = { aa0[0], aa1[0], aa2[0], aa3[0] };
    float* op = out + (size_t)b * SB_ + (size_t)u * SU_ + (size_t)v * SV_ + w0 + n;
    const bool act = (q < 2);
#pragma unroll
    for (int br = 0; br < 4; ++br) {
        const float* bp = (br == 0) ? bb0 : (br == 1) ? bb1 : (br == 2) ? bb2 : bb3;
        const f32x4 bv = *(const f32x4*)(bp + (q & 1) * 4);
#pragma unroll
        for (int hh = 0; hh < 2; ++hh) {
            const int h = h0 + rbase + hh;
#pragma unroll
            for (int r = 0; r < 4; ++r) {
                float val = acc[br][hh][r] + bv[r];
                val = (val >= 0.f) ? val : alph[br] * val;
                if (act)
                    op[(size_t)(br * 8 + q * 4 + r) * SC_ + (size_t)h * 64] = val;
            }
        }
    }
}

extern "C" void kernel_launch(void* const* d_in, const int* in_sizes, int n_in,
                              void* d_out, int out_size, void* d_ws, size_t ws_size,
                              hipStream_t stream) {
    const float* x  = (const float*)d_in[0];
    const float* w0 = (const float*)d_in[1];
    const float* b0 = (const float*)d_in[2];
    const float* a0 = (const float*)d_in[3];
    const float* w1 = (const float*)d_in[4];
    const float* b1 = (const float*)d_in[5];
    const float* a1 = (const float*)d_in[6];
    const float* w2 = (const float*)d_in[7];
    const float* b2 = (const float*)d_in[8];
    const float* a2 = (const float*)d_in[9];
    const float* w3 = (const float*)d_in[10];
    const float* b3 = (const float*)d_in[11];
    const float* a3 = (const float*)d_in[12];
    float* out = (float*)d_out;

    unsigned short* xT = (unsigned short*)d_ws;
    unsigned short* bt = (unsigned short*)((char*)d_ws + BT_OFF);

    k_weights<<<108, 256, 0, stream>>>(w0, w1, w2, w3, bt);
    k_transpose<<<B_ * U_ * V_ * (H_ / 4), 256, 0, stream>>>(x, xT);   // 3200 blocks
    k_main<<<B_ * U_ * V_ * (H_ / 4), 512, 0, stream>>>(               // 3200 blocks
        xT, bt, b0, a0, b1, a1, b2, a2, b3, a3, out);
}